// Round 1
// baseline (102.824 us; speedup 1.0000x reference)
//
#include <hip/hip_runtime.h>

typedef __attribute__((ext_vector_type(8)))  short short8;
typedef __attribute__((ext_vector_type(16))) float f32x16;
typedef __attribute__((ext_vector_type(4)))  float f32x4;
typedef __attribute__((ext_vector_type(2)))  float f32x2;

union U8 { short8 s; unsigned u[4]; };

__device__ __forceinline__ unsigned short f2bf(float x){
  unsigned u = __float_as_uint(x);
  u += 0x7fffu + ((u >> 16) & 1u);          // RNE
  return (unsigned short)(u >> 16);
}
__device__ __forceinline__ unsigned pk2(float lo, float hi){
  return (unsigned)f2bf(lo) | ((unsigned)f2bf(hi) << 16);
}
__device__ __forceinline__ void swap32(unsigned &a, unsigned &b){
  // exchanges a's hi-half lanes with b's lo-half lanes (cross-positioned)
  asm("v_permlane32_swap_b32 %0, %1" : "+v"(a), "+v"(b));
}

#define MFMA32(a,b,c) __builtin_amdgcn_mfma_f32_32x32x16_bf16((a),(b),(c),0,0,0)

// LDS (64 KiB):
//  [0,32768):      2 x K tile  (64 keys x 128 feat bf16, 16B blocks XOR (key&7))
//  [32768,65536):  2 x Vt tile (128 d x 64 kv bf16, 16B blocks XOR ((d>>4)&7)^(d&7))
// Epilogue reuses [w*16384, +16KB) per wave.

__device__ __forceinline__ void stage_tile(char* sm, int buf, const float* __restrict__ Kg,
                                           const float* __restrict__ Vg, int kv0, int tid)
{
  { // K tile: f32 -> bf16, row-major, swizzled
    const int key = tid >> 2;
    const int c0  = (tid & 3) * 4;                 // 16B blocks (8 feats each)
    const float* kp = Kg + (kv0 + key) * 128 + c0 * 8;
    f32x4 ka[8];
#pragma unroll
    for (int i = 0; i < 8; ++i) ka[i] = *(const f32x4*)(kp + i * 4);
    char* kb = sm + buf * 16384 + key * 256;
#pragma unroll
    for (int i = 0; i < 4; ++i) {
      U8 u;
      u.u[0] = pk2(ka[2*i].x,   ka[2*i].y);
      u.u[1] = pk2(ka[2*i].z,   ka[2*i].w);
      u.u[2] = pk2(ka[2*i+1].x, ka[2*i+1].y);
      u.u[3] = pk2(ka[2*i+1].z, ka[2*i+1].w);
      *(short8*)(kb + (((c0 + i) ^ (key & 7)) * 16)) = u.s;
    }
  }
  { // V tile: transpose into Vt[d][kv], pair-writes (kv,kv+1) as b32, swizzled
    const int kvp = (tid >> 3) * 2;
    const int d0  = (tid & 7) * 16;
    const float* vp = Vg + (kv0 + kvp) * 128 + d0;
    f32x4 va[4], vb[4];
#pragma unroll
    for (int i = 0; i < 4; ++i) {
      va[i] = *(const f32x4*)(vp + i * 4);
      vb[i] = *(const f32x4*)(vp + 128 + i * 4);
    }
    char* vbse = sm + 32768 + buf * 16384;
#pragma unroll
    for (int j = 0; j < 16; ++j) {
      const int d  = d0 + j;
      const unsigned wv = pk2(va[j >> 2][j & 3], vb[j >> 2][j & 3]);
      const int bp = (kvp >> 3) ^ ((d >> 4) & 7) ^ (d & 7);
      *(unsigned*)(vbse + d * 128 + bp * 16 + (kvp & 7) * 2) = wv;
    }
  }
}

__launch_bounds__(256, 1)
__global__ void attn_fused(const float* __restrict__ Q, const float* __restrict__ K,
                           const float* __restrict__ V, const int* __restrict__ VL,
                           float* __restrict__ Out, int Lq, int Lk)
{
  __shared__ __align__(16) char sm[65536];
  const int tid  = threadIdx.x;
  const int lane = tid & 63;
  const int w    = tid >> 6;
  const int lq   = lane & 31;
  const int hi   = lane >> 5;
  const int b    = blockIdx.y;
  const int vlb  = VL[b];
  const int nt   = (vlb + 63) >> 6;
  const float SCL2 = 0.08838834764831845f * 1.4426950408889634f; // 1/sqrt(128)*log2(e)

  const float* Kg = K + (size_t)b * Lk * 128;
  const float* Vg = V + (size_t)b * Lk * 128;
  const int qrow  = blockIdx.x * 128 + w * 32 + lq;
  const float* Qg = Q + ((size_t)b * Lq + qrow) * 128;

  // Q fragments: lane holds Q[q=lq][feat = s8*16 + hi*8 + 0..7]
  short8 qf[8];
#pragma unroll
  for (int s8 = 0; s8 < 8; ++s8) {
    f32x4 a = *(const f32x4*)(Qg + s8 * 16 + hi * 8);
    f32x4 c = *(const f32x4*)(Qg + s8 * 16 + hi * 8 + 4);
    U8 u;
    u.u[0] = pk2(a.x, a.y); u.u[1] = pk2(a.z, a.w);
    u.u[2] = pk2(c.x, c.y); u.u[3] = pk2(c.z, c.w);
    qf[s8] = u.s;
  }

  f32x16 accO[4];
#pragma unroll
  for (int i = 0; i < 4; ++i)
#pragma unroll
    for (int r = 0; r < 16; ++r) accO[i][r] = 0.0f;

  float mrun = -1e30f, lsum = 0.0f;

  stage_tile(sm, 0, Kg, Vg, 0, tid);

  for (int t = 0; t < nt; ++t) {
    __syncthreads();
    const int kbase = (t & 1) * 16384;
    const int vbase = 32768 + (t & 1) * 16384;

    // ---- S^T = mfma(K, Q): lane holds S[q=lq][16 keys] per 32-key tile ----
    f32x16 s0, s1;
#pragma unroll
    for (int r = 0; r < 16; ++r) { s0[r] = 0.0f; s1[r] = 0.0f; }
#pragma unroll
    for (int s8 = 0; s8 < 8; ++s8) {
      const int blk = 2 * s8 + hi;
      short8 k0 = *(const short8*)(sm + kbase + lq * 256        + ((blk ^ (lq & 7)) * 16));
      short8 k1 = *(const short8*)(sm + kbase + (32 + lq) * 256 + ((blk ^ (lq & 7)) * 16));
      s0 = MFMA32(k0, qf[s8], s0);
      s1 = MFMA32(k1, qf[s8], s1);
    }

    // ---- valid_len mask (last, partial tile only) ----
    if (t == nt - 1 && (vlb & 63)) {
      const int kb = t * 64 + 4 * hi;
#pragma unroll
      for (int r = 0; r < 16; ++r) {
        const int key = kb + (r & 3) + 8 * (r >> 2);
        if (key >= vlb)      s0[r] = -1e30f;
        if (key + 32 >= vlb) s1[r] = -1e30f;
      }
    }

    // ---- online softmax (lane owns row q=lq; combine halves via xor-32) ----
    float tmax = -1e30f;
#pragma unroll
    for (int r = 0; r < 16; ++r) { tmax = fmaxf(tmax, s0[r]); tmax = fmaxf(tmax, s1[r]); }
    tmax = fmaxf(tmax, __shfl_xor(tmax, 32, 64));
    const float mnew = fmaxf(mrun, tmax);
    const float mk   = mnew * SCL2;
    float tsum = 0.0f;
#pragma unroll
    for (int r = 0; r < 16; ++r) {
      s0[r] = __builtin_amdgcn_exp2f(s0[r] * SCL2 - mk); tsum += s0[r];
      s1[r] = __builtin_amdgcn_exp2f(s1[r] * SCL2 - mk); tsum += s1[r];
    }
    tsum += __shfl_xor(tsum, 32, 64);
    if (__any(mnew > mrun)) {
      const float corr = __builtin_amdgcn_exp2f((mrun - mnew) * SCL2);
      lsum = lsum * corr + tsum;
#pragma unroll
      for (int i = 0; i < 4; ++i)
#pragma unroll
        for (int r = 0; r < 16; ++r) accO[i][r] *= corr;
    } else {
      lsum += tsum;
    }
    mrun = mnew;

    // prefetch next tile (global f32 loads hide under PV below)
    if (t + 1 < nt) stage_tile(sm, (t + 1) & 1, Kg, Vg, (t + 1) * 64, tid);

    // ---- P -> bf16 B-fragments: cvt-pack + permlane32_swap (in-register) ----
    U8 pf[4];
    {
      unsigned wt[8]; unsigned a, bx;
#pragma unroll
      for (int j = 0; j < 8; ++j) wt[j] = pk2(s0[2*j], s0[2*j+1]);
      a = wt[0]; bx = wt[2]; swap32(a, bx); pf[0].u[0] = a; pf[0].u[2] = bx;
      a = wt[1]; bx = wt[3]; swap32(a, bx); pf[0].u[1] = a; pf[0].u[3] = bx;
      a = wt[4]; bx = wt[6]; swap32(a, bx); pf[1].u[0] = a; pf[1].u[2] = bx;
      a = wt[5]; bx = wt[7]; swap32(a, bx); pf[1].u[1] = a; pf[1].u[3] = bx;
#pragma unroll
      for (int j = 0; j < 8; ++j) wt[j] = pk2(s1[2*j], s1[2*j+1]);
      a = wt[0]; bx = wt[2]; swap32(a, bx); pf[2].u[0] = a; pf[2].u[2] = bx;
      a = wt[1]; bx = wt[3]; swap32(a, bx); pf[2].u[1] = a; pf[2].u[3] = bx;
      a = wt[4]; bx = wt[6]; swap32(a, bx); pf[3].u[0] = a; pf[3].u[2] = bx;
      a = wt[5]; bx = wt[7]; swap32(a, bx); pf[3].u[1] = a; pf[3].u[3] = bx;
    }

    // ---- O^T += mfma(Vt, P): lane accumulates O[q=lq][d per reg] ----
#pragma unroll
    for (int s = 0; s < 4; ++s) {
#pragma unroll
      for (int dt = 0; dt < 4; ++dt) {
        const int d  = dt * 32 + lq;
        const int bp = (2 * s + hi) ^ ((d >> 4) & 7) ^ (d & 7);
        short8 vf = *(const short8*)(sm + vbase + d * 128 + bp * 16);
        accO[dt] = MFMA32(vf, pf[s].s, accO[dt]);
      }
    }
  }

  // ---- epilogue: per-wave LDS transpose, coalesced f32 stores ----
  __syncthreads();
  const float inv = 1.0f / lsum;
  char* eb = sm + w * 16384;
#pragma unroll
  for (int dt = 0; dt < 4; ++dt) {
#pragma unroll
    for (int r = 0; r < 16; r += 2) {
      const int d = dt * 32 + (r & 3) + 8 * (r >> 2) + 4 * hi;
      f32x2 o2; o2.x = accO[dt][r] * inv; o2.y = accO[dt][r+1] * inv;
      *(f32x2*)(eb + lq * 512 + (((d >> 2) ^ (lq & 7)) * 16) + (d & 3) * 4) = o2;
    }
  }
  float* Og = Out + ((size_t)b * Lq + blockIdx.x * 128 + w * 32) * 128;
#pragma unroll
  for (int pass = 0; pass < 16; ++pass) {
    const int q = pass * 2 + hi;
    f32x4 o4 = *(const f32x4*)(eb + q * 512 + ((lq ^ (q & 7)) * 16));
    *(f32x4*)(Og + q * 128 + lq * 4) = o4;
  }
}

extern "C" void kernel_launch(void* const* d_in, const int* in_sizes, int n_in,
                              void* d_out, int out_size, void* d_ws, size_t ws_size,
                              hipStream_t stream)
{
  (void)n_in; (void)out_size; (void)d_ws; (void)ws_size;
  const float* Q  = (const float*)d_in[0];
  const float* K  = (const float*)d_in[1];
  const float* V  = (const float*)d_in[2];
  const int*   VL = (const int*)d_in[3];
  float* Out = (float*)d_out;
  const int B  = in_sizes[3];
  const int Lq = in_sizes[0] / (B * 128);
  const int Lk = in_sizes[1] / (B * 128);
  dim3 grid(Lq / 128, B);
  attn_fused<<<grid, 256, 0, stream>>>(Q, K, V, VL, Out, Lq, Lk);
}

// Round 2
// 74.035 us; speedup vs baseline: 1.3889x; 1.3889x over previous
//
#include <hip/hip_runtime.h>
#include <stdint.h>

typedef __attribute__((ext_vector_type(8)))  short short8;
typedef __attribute__((ext_vector_type(16))) float f32x16;
typedef __attribute__((ext_vector_type(4)))  float f32x4;
typedef __attribute__((ext_vector_type(2)))  float f32x2;

union U8 { short8 s; unsigned u[4]; };

__device__ __forceinline__ unsigned short f2bf(float x){
  unsigned u = __float_as_uint(x);
  u += 0x7fffu + ((u >> 16) & 1u);          // RNE
  return (unsigned short)(u >> 16);
}
__device__ __forceinline__ unsigned pk2(float lo, float hi){
  return (unsigned)f2bf(lo) | ((unsigned)f2bf(hi) << 16);
}
__device__ __forceinline__ void swap32(unsigned &a, unsigned &b){
  asm("v_permlane32_swap_b32 %0, %1" : "+v"(a), "+v"(b));
}

#define MFMA32(a,b,c) __builtin_amdgcn_mfma_f32_32x32x16_bf16((a),(b),(c),0,0,0)

// ============================================================================
// Pre-pass: K -> bf16 tiles in swizzled row-major layout (64 keys x 128 feat,
// 16B block c stored at c ^ (key&7)); V -> Vt bf16 (128 d x 64 kv, kv-pairs,
// 16B block k8 stored at k8 ^ ((d>>4)&7) ^ (d&7)). One 16 KiB tile per
// (batch, 64-kv tile) each for K and V. Main kernel then stages tiles with
// global_load_lds (linear copy; swizzle pre-baked).
// ============================================================================
__global__ void prep_kv(const float* __restrict__ K, const float* __restrict__ V,
                        const int* __restrict__ VL,
                        char* __restrict__ Kws, char* __restrict__ Vws, int Lk)
{
  const int b = blockIdx.y, t = blockIdx.x, tid = threadIdx.x;
  if (t * 64 >= VL[b]) return;                    // tiles past valid_len never read
  const int kv0 = t * 64;
  const size_t tbase = ((size_t)b * (Lk >> 6) + t) << 14;  // 16 KiB per tile
  const float* Kg = K + ((size_t)b * Lk + kv0) * 128;
  const float* Vg = V + ((size_t)b * Lk + kv0) * 128;
  { // K tile
    const int key = tid >> 2;
    const int c0  = (tid & 3) * 4;
    const float* kp = Kg + key * 128 + c0 * 8;
    f32x4 ka[8];
#pragma unroll
    for (int i = 0; i < 8; ++i) ka[i] = *(const f32x4*)(kp + i * 4);
    char* kb = Kws + tbase + key * 256;
#pragma unroll
    for (int i = 0; i < 4; ++i) {
      U8 u;
      u.u[0] = pk2(ka[2*i].x,   ka[2*i].y);
      u.u[1] = pk2(ka[2*i].z,   ka[2*i].w);
      u.u[2] = pk2(ka[2*i+1].x, ka[2*i+1].y);
      u.u[3] = pk2(ka[2*i+1].z, ka[2*i+1].w);
      *(short8*)(kb + (((c0 + i) ^ (key & 7)) * 16)) = u.s;
    }
  }
  { // V tile (transposed)
    const int kvp = (tid >> 3) * 2;
    const int d0  = (tid & 7) * 16;
    const float* vp = Vg + kvp * 128 + d0;
    f32x4 va[4], vb[4];
#pragma unroll
    for (int i = 0; i < 4; ++i) {
      va[i] = *(const f32x4*)(vp + i * 4);
      vb[i] = *(const f32x4*)(vp + 128 + i * 4);
    }
    char* vbse = Vws + tbase;
#pragma unroll
    for (int j = 0; j < 16; ++j) {
      const int d  = d0 + j;
      const unsigned wv = pk2(va[j >> 2][j & 3], vb[j >> 2][j & 3]);
      const int bp = (kvp >> 3) ^ ((d >> 4) & 7) ^ (d & 7);
      *(unsigned*)(vbse + d * 128 + bp * 16 + (kvp & 7) * 2) = wv;
    }
  }
}

// ============================================================================
// Main fused attention reading pre-converted bf16 tiles from ws.
// LDS: [0,32768) 2 x K buf; [32768,65536) 2 x Vt buf. One barrier per tile
// (m97 pattern: issue t+1 after top-of-tile barrier; syncthreads drains vmcnt).
// ============================================================================
__device__ __forceinline__ void issue_tile(char* sm, const char* Kt, const char* Vt,
                                           int t, int w, int lane)
{
  const size_t goff = ((size_t)t << 14) + (size_t)(w * 4096 + lane * 16);
  const char* gk = Kt + goff;
  const char* gv = Vt + goff;
  char* lk = sm + ((t & 1) << 14) + w * 4096;
  char* lv = sm + 32768 + ((t & 1) << 14) + w * 4096;
#pragma unroll
  for (int i = 0; i < 4; ++i) {
    __builtin_amdgcn_global_load_lds((const __attribute__((address_space(1))) void*)(gk + i * 1024),
                                     (__attribute__((address_space(3))) void*)(lk + i * 1024), 16, 0, 0);
    __builtin_amdgcn_global_load_lds((const __attribute__((address_space(1))) void*)(gv + i * 1024),
                                     (__attribute__((address_space(3))) void*)(lv + i * 1024), 16, 0, 0);
  }
}

__launch_bounds__(256, 1)
__global__ void attn_ws(const float* __restrict__ Q, const char* __restrict__ Kws,
                        const char* __restrict__ Vws, const int* __restrict__ VL,
                        float* __restrict__ Out, int Lq, int Lk)
{
  __shared__ __align__(16) char sm[65536];
  const int tid  = threadIdx.x;
  const int lane = tid & 63;
  const int w    = tid >> 6;
  const int lq   = lane & 31;
  const int hi   = lane >> 5;

  // XCD-locality swizzle: batch b pinned to XCD b&7 (2 batches/XCD; K+V bf16
  // for 2 batches = 2.1 MB < 4 MiB L2). Bijective over 256 blocks.
  int qt, b;
  if (gridDim.x == 256 && gridDim.y == 1) {
    const int bid = blockIdx.x;
    b  = (bid & 7) | (((bid >> 3) & 1) << 3);
    qt = bid >> 4;
  } else { qt = blockIdx.x; b = blockIdx.y; }

  const int vlb = VL[b];
  const int nt  = (vlb + 63) >> 6;
  const float SCL2 = 0.08838834764831845f * 1.4426950408889634f; // 1/sqrt(128)*log2(e)

  const char* Ktiles = Kws + (((size_t)b * (Lk >> 6)) << 14);
  const char* Vtiles = Vws + (((size_t)b * (Lk >> 6)) << 14);
  const int qrow  = qt * 128 + w * 32 + lq;
  const float* Qg = Q + ((size_t)b * Lq + qrow) * 128;

  // prologue: stage tile 0
  issue_tile(sm, Ktiles, Vtiles, 0, w, lane);

  // Q fragments: lane holds Q[q=lq][feat = s8*16 + hi*8 + 0..7]
  short8 qf[8];
#pragma unroll
  for (int s8 = 0; s8 < 8; ++s8) {
    f32x4 a = *(const f32x4*)(Qg + s8 * 16 + hi * 8);
    f32x4 c = *(const f32x4*)(Qg + s8 * 16 + hi * 8 + 4);
    U8 u;
    u.u[0] = pk2(a.x, a.y); u.u[1] = pk2(a.z, a.w);
    u.u[2] = pk2(c.x, c.y); u.u[3] = pk2(c.z, c.w);
    qf[s8] = u.s;
  }

  f32x16 accO[4];
#pragma unroll
  for (int i = 0; i < 4; ++i)
#pragma unroll
    for (int r = 0; r < 16; ++r) accO[i][r] = 0.0f;

  float mrun = -1e30f, lsum = 0.0f;

  for (int t = 0; t < nt; ++t) {
    __syncthreads();   // drains this wave's gload_lds (tile t) + barrier
    if (t + 1 < nt) issue_tile(sm, Ktiles, Vtiles, t + 1, w, lane);

    const int kbase = (t & 1) << 14;
    const int vbase = 32768 + ((t & 1) << 14);

    // ---- S^T = mfma(K, Q): lane holds S[q=lq][16 keys] per 32-key tile ----
    f32x16 s0, s1;
#pragma unroll
    for (int r = 0; r < 16; ++r) { s0[r] = 0.0f; s1[r] = 0.0f; }
#pragma unroll
    for (int s8 = 0; s8 < 8; ++s8) {
      const int blk = 2 * s8 + hi;
      short8 k0 = *(const short8*)(sm + kbase + lq * 256        + ((blk ^ (lq & 7)) * 16));
      short8 k1 = *(const short8*)(sm + kbase + (32 + lq) * 256 + ((blk ^ (lq & 7)) * 16));
      s0 = MFMA32(k0, qf[s8], s0);
      s1 = MFMA32(k1, qf[s8], s1);
    }

    // ---- valid_len mask (last, partial tile only) ----
    if (t == nt - 1 && (vlb & 63)) {
      const int kb = t * 64 + 4 * hi;
#pragma unroll
      for (int r = 0; r < 16; ++r) {
        const int key = kb + (r & 3) + 8 * (r >> 2);
        if (key >= vlb)      s0[r] = -1e30f;
        if (key + 32 >= vlb) s1[r] = -1e30f;
      }
    }

    // ---- online softmax (lane owns row q=lq; combine halves via xor-32) ----
    float tmax = -1e30f;
#pragma unroll
    for (int r = 0; r < 16; ++r) { tmax = fmaxf(tmax, s0[r]); tmax = fmaxf(tmax, s1[r]); }
    tmax = fmaxf(tmax, __shfl_xor(tmax, 32, 64));
    const float mnew = fmaxf(mrun, tmax);
    const float mk   = mnew * SCL2;
    float tsum = 0.0f;
#pragma unroll
    for (int r = 0; r < 16; ++r) {
      s0[r] = __builtin_amdgcn_exp2f(s0[r] * SCL2 - mk); tsum += s0[r];
      s1[r] = __builtin_amdgcn_exp2f(s1[r] * SCL2 - mk); tsum += s1[r];
    }
    tsum += __shfl_xor(tsum, 32, 64);
    if (__any(mnew > mrun)) {
      const float corr = __builtin_amdgcn_exp2f((mrun - mnew) * SCL2);
      lsum = lsum * corr + tsum;
#pragma unroll
      for (int i = 0; i < 4; ++i)
#pragma unroll
        for (int r = 0; r < 16; ++r) accO[i][r] *= corr;
    } else {
      lsum += tsum;
    }
    mrun = mnew;

    // ---- P -> bf16 B-fragments: cvt-pack + permlane32_swap (in-register) ----
    U8 pf[4];
    {
      unsigned wt[8]; unsigned a, bx;
#pragma unroll
      for (int j = 0; j < 8; ++j) wt[j] = pk2(s0[2*j], s0[2*j+1]);
      a = wt[0]; bx = wt[2]; swap32(a, bx); pf[0].u[0] = a; pf[0].u[2] = bx;
      a = wt[1]; bx = wt[3]; swap32(a, bx); pf[0].u[1] = a; pf[0].u[3] = bx;
      a = wt[4]; bx = wt[6]; swap32(a, bx); pf[1].u[0] = a; pf[1].u[2] = bx;
      a = wt[5]; bx = wt[7]; swap32(a, bx); pf[1].u[1] = a; pf[1].u[3] = bx;
#pragma unroll
      for (int j = 0; j < 8; ++j) wt[j] = pk2(s1[2*j], s1[2*j+1]);
      a = wt[0]; bx = wt[2]; swap32(a, bx); pf[2].u[0] = a; pf[2].u[2] = bx;
      a = wt[1]; bx = wt[3]; swap32(a, bx); pf[2].u[1] = a; pf[2].u[3] = bx;
      a = wt[4]; bx = wt[6]; swap32(a, bx); pf[3].u[0] = a; pf[3].u[2] = bx;
      a = wt[5]; bx = wt[7]; swap32(a, bx); pf[3].u[1] = a; pf[3].u[3] = bx;
    }

    // ---- O^T += mfma(Vt, P): lane accumulates O[q=lq][d per reg] ----
#pragma unroll
    for (int s = 0; s < 4; ++s) {
#pragma unroll
      for (int dt = 0; dt < 4; ++dt) {
        const int d  = dt * 32 + lq;
        const int bp = (2 * s + hi) ^ ((d >> 4) & 7) ^ (d & 7);
        short8 vf = *(const short8*)(sm + vbase + d * 128 + bp * 16);
        accO[dt] = MFMA32(vf, pf[s].s, accO[dt]);
      }
    }
  }

  // ---- epilogue: per-wave LDS transpose, coalesced f32 stores ----
  __syncthreads();
  const float inv = 1.0f / lsum;
  char* eb = sm + w * 16384;
#pragma unroll
  for (int dt = 0; dt < 4; ++dt) {
#pragma unroll
    for (int r = 0; r < 16; r += 2) {
      const int d = dt * 32 + (r & 3) + 8 * (r >> 2) + 4 * hi;
      f32x2 o2; o2.x = accO[dt][r] * inv; o2.y = accO[dt][r+1] * inv;
      *(f32x2*)(eb + lq * 512 + (((d >> 2) ^ (lq & 7)) * 16) + (d & 3) * 4) = o2;
    }
  }
  float* Og = Out + ((size_t)b * Lq + qt * 128 + w * 32) * 128;
#pragma unroll
  for (int pass = 0; pass < 16; ++pass) {
    const int q = pass * 2 + hi;
    f32x4 o4 = *(const f32x4*)(eb + q * 512 + ((lq ^ (q & 7)) * 16));
    *(f32x4*)(Og + q * 128 + lq * 4) = o4;
  }
}

// ============================================================================
// Fallback (round-1 kernel, verified): used only if ws_size is too small.
// ============================================================================
__device__ __forceinline__ void stage_tile(char* sm, int buf, const float* __restrict__ Kg,
                                           const float* __restrict__ Vg, int kv0, int tid)
{
  {
    const int key = tid >> 2;
    const int c0  = (tid & 3) * 4;
    const float* kp = Kg + (kv0 + key) * 128 + c0 * 8;
    f32x4 ka[8];
#pragma unroll
    for (int i = 0; i < 8; ++i) ka[i] = *(const f32x4*)(kp + i * 4);
    char* kb = sm + buf * 16384 + key * 256;
#pragma unroll
    for (int i = 0; i < 4; ++i) {
      U8 u;
      u.u[0] = pk2(ka[2*i].x,   ka[2*i].y);
      u.u[1] = pk2(ka[2*i].z,   ka[2*i].w);
      u.u[2] = pk2(ka[2*i+1].x, ka[2*i+1].y);
      u.u[3] = pk2(ka[2*i+1].z, ka[2*i+1].w);
      *(short8*)(kb + (((c0 + i) ^ (key & 7)) * 16)) = u.s;
    }
  }
  {
    const int kvp = (tid >> 3) * 2;
    const int d0  = (tid & 7) * 16;
    const float* vp = Vg + (kv0 + kvp) * 128 + d0;
    f32x4 va[4], vb[4];
#pragma unroll
    for (int i = 0; i < 4; ++i) {
      va[i] = *(const f32x4*)(vp + i * 4);
      vb[i] = *(const f32x4*)(vp + 128 + i * 4);
    }
    char* vbse = sm + 32768 + buf * 16384;
#pragma unroll
    for (int j = 0; j < 16; ++j) {
      const int d  = d0 + j;
      const unsigned wv = pk2(va[j >> 2][j & 3], vb[j >> 2][j & 3]);
      const int bp = (kvp >> 3) ^ ((d >> 4) & 7) ^ (d & 7);
      *(unsigned*)(vbse + d * 128 + bp * 16 + (kvp & 7) * 2) = wv;
    }
  }
}

__launch_bounds__(256, 1)
__global__ void attn_fused(const float* __restrict__ Q, const float* __restrict__ K,
                           const float* __restrict__ V, const int* __restrict__ VL,
                           float* __restrict__ Out, int Lq, int Lk)
{
  __shared__ __align__(16) char sm[65536];
  const int tid  = threadIdx.x;
  const int lane = tid & 63;
  const int w    = tid >> 6;
  const int lq   = lane & 31;
  const int hi   = lane >> 5;
  const int b    = blockIdx.y;
  const int vlb  = VL[b];
  const int nt   = (vlb + 63) >> 6;
  const float SCL2 = 0.08838834764831845f * 1.4426950408889634f;

  const float* Kg = K + (size_t)b * Lk * 128;
  const float* Vg = V + (size_t)b * Lk * 128;
  const int qrow  = blockIdx.x * 128 + w * 32 + lq;
  const float* Qg = Q + ((size_t)b * Lq + qrow) * 128;

  short8 qf[8];
#pragma unroll
  for (int s8 = 0; s8 < 8; ++s8) {
    f32x4 a = *(const f32x4*)(Qg + s8 * 16 + hi * 8);
    f32x4 c = *(const f32x4*)(Qg + s8 * 16 + hi * 8 + 4);
    U8 u;
    u.u[0] = pk2(a.x, a.y); u.u[1] = pk2(a.z, a.w);
    u.u[2] = pk2(c.x, c.y); u.u[3] = pk2(c.z, c.w);
    qf[s8] = u.s;
  }

  f32x16 accO[4];
#pragma unroll
  for (int i = 0; i < 4; ++i)
#pragma unroll
    for (int r = 0; r < 16; ++r) accO[i][r] = 0.0f;

  float mrun = -1e30f, lsum = 0.0f;
  stage_tile(sm, 0, Kg, Vg, 0, tid);

  for (int t = 0; t < nt; ++t) {
    __syncthreads();
    const int kbase = (t & 1) * 16384;
    const int vbase = 32768 + (t & 1) * 16384;

    f32x16 s0, s1;
#pragma unroll
    for (int r = 0; r < 16; ++r) { s0[r] = 0.0f; s1[r] = 0.0f; }
#pragma unroll
    for (int s8 = 0; s8 < 8; ++s8) {
      const int blk = 2 * s8 + hi;
      short8 k0 = *(const short8*)(sm + kbase + lq * 256        + ((blk ^ (lq & 7)) * 16));
      short8 k1 = *(const short8*)(sm + kbase + (32 + lq) * 256 + ((blk ^ (lq & 7)) * 16));
      s0 = MFMA32(k0, qf[s8], s0);
      s1 = MFMA32(k1, qf[s8], s1);
    }

    if (t == nt - 1 && (vlb & 63)) {
      const int kb = t * 64 + 4 * hi;
#pragma unroll
      for (int r = 0; r < 16; ++r) {
        const int key = kb + (r & 3) + 8 * (r >> 2);
        if (key >= vlb)      s0[r] = -1e30f;
        if (key + 32 >= vlb) s1[r] = -1e30f;
      }
    }

    float tmax = -1e30f;
#pragma unroll
    for (int r = 0; r < 16; ++r) { tmax = fmaxf(tmax, s0[r]); tmax = fmaxf(tmax, s1[r]); }
    tmax = fmaxf(tmax, __shfl_xor(tmax, 32, 64));
    const float mnew = fmaxf(mrun, tmax);
    const float mk   = mnew * SCL2;
    float tsum = 0.0f;
#pragma unroll
    for (int r = 0; r < 16; ++r) {
      s0[r] = __builtin_amdgcn_exp2f(s0[r] * SCL2 - mk); tsum += s0[r];
      s1[r] = __builtin_amdgcn_exp2f(s1[r] * SCL2 - mk); tsum += s1[r];
    }
    tsum += __shfl_xor(tsum, 32, 64);
    if (__any(mnew > mrun)) {
      const float corr = __builtin_amdgcn_exp2f((mrun - mnew) * SCL2);
      lsum = lsum * corr + tsum;
#pragma unroll
      for (int i = 0; i < 4; ++i)
#pragma unroll
        for (int r = 0; r < 16; ++r) accO[i][r] *= corr;
    } else {
      lsum += tsum;
    }
    mrun = mnew;

    if (t + 1 < nt) stage_tile(sm, (t + 1) & 1, Kg, Vg, (t + 1) * 64, tid);

    U8 pf[4];
    {
      unsigned wt[8]; unsigned a, bx;
#pragma unroll
      for (int j = 0; j < 8; ++j) wt[j] = pk2(s0[2*j], s0[2*j+1]);
      a = wt[0]; bx = wt[2]; swap32(a, bx); pf[0].u[0] = a; pf[0].u[2] = bx;
      a = wt[1]; bx = wt[3]; swap32(a, bx); pf[0].u[1] = a; pf[0].u[3] = bx;
      a = wt[4]; bx = wt[6]; swap32(a, bx); pf[1].u[0] = a; pf[1].u[2] = bx;
      a = wt[5]; bx = wt[7]; swap32(a, bx); pf[1].u[1] = a; pf[1].u[3] = bx;
#pragma unroll
      for (int j = 0; j < 8; ++j) wt[j] = pk2(s1[2*j], s1[2*j+1]);
      a = wt[0]; bx = wt[2]; swap32(a, bx); pf[2].u[0] = a; pf[2].u[2] = bx;
      a = wt[1]; bx = wt[3]; swap32(a, bx); pf[2].u[1] = a; pf[2].u[3] = bx;
      a = wt[4]; bx = wt[6]; swap32(a, bx); pf[3].u[0] = a; pf[3].u[2] = bx;
      a = wt[5]; bx = wt[7]; swap32(a, bx); pf[3].u[1] = a; pf[3].u[3] = bx;
    }

#pragma unroll
    for (int s = 0; s < 4; ++s) {
#pragma unroll
      for (int dt = 0; dt < 4; ++dt) {
        const int d  = dt * 32 + lq;
        const int bp = (2 * s + hi) ^ ((d >> 4) & 7) ^ (d & 7);
        short8 vf = *(const short8*)(sm + vbase + d * 128 + bp * 16);
        accO[dt] = MFMA32(vf, pf[s].s, accO[dt]);
      }
    }
  }

  __syncthreads();
  const float inv = 1.0f / lsum;
  char* eb = sm + w * 16384;
#pragma unroll
  for (int dt = 0; dt < 4; ++dt) {
#pragma unroll
    for (int r = 0; r < 16; r += 2) {
      const int d = dt * 32 + (r & 3) + 8 * (r >> 2) + 4 * hi;
      f32x2 o2; o2.x = accO[dt][r] * inv; o2.y = accO[dt][r+1] * inv;
      *(f32x2*)(eb + lq * 512 + (((d >> 2) ^ (lq & 7)) * 16) + (d & 3) * 4) = o2;
    }
  }
  float* Og = Out + ((size_t)b * Lq + blockIdx.x * 128 + w * 32) * 128;
#pragma unroll
  for (int pass = 0; pass < 16; ++pass) {
    const int q = pass * 2 + hi;
    f32x4 o4 = *(const f32x4*)(eb + q * 512 + ((lq ^ (q & 7)) * 16));
    *(f32x4*)(Og + q * 128 + lq * 4) = o4;
  }
}

extern "C" void kernel_launch(void* const* d_in, const int* in_sizes, int n_in,
                              void* d_out, int out_size, void* d_ws, size_t ws_size,
                              hipStream_t stream)
{
  (void)n_in; (void)out_size;
  const float* Q  = (const float*)d_in[0];
  const float* K  = (const float*)d_in[1];
  const float* V  = (const float*)d_in[2];
  const int*   VL = (const int*)d_in[3];
  float* Out = (float*)d_out;
  const int B  = in_sizes[3];
  const int Lq = in_sizes[0] / (B * 128);
  const int Lk = in_sizes[1] / (B * 128);

  const size_t kbytes = (size_t)B * Lk * 256;   // bf16 swizzled K tiles
  const size_t need   = kbytes * 2;             // + Vt tiles
  if (ws_size >= need && (Lk & 63) == 0 && (Lq & 127) == 0) {
    char* Kws = (char*)d_ws;
    char* Vws = Kws + kbytes;
    dim3 pg(Lk / 64, B);
    prep_kv<<<pg, 256, 0, stream>>>(K, V, VL, Kws, Vws, Lk);
    if (Lq == 2048 && B == 16) {
      attn_ws<<<256, 256, 0, stream>>>(Q, Kws, Vws, VL, Out, Lq, Lk);
    } else {
      dim3 g(Lq / 128, B);
      attn_ws<<<g, 256, 0, stream>>>(Q, Kws, Vws, VL, Out, Lq, Lk);
    }
  } else {
    dim3 g(Lq / 128, B);
    attn_fused<<<g, 256, 0, stream>>>(Q, K, V, VL, Out, Lq, Lk);
  }
}

// Round 4
// 58.116 us; speedup vs baseline: 1.7693x; 1.2739x over previous
//
#include <hip/hip_runtime.h>
#include <stdint.h>

typedef __attribute__((ext_vector_type(8)))  short short8;
typedef __attribute__((ext_vector_type(16))) float f32x16;
typedef __attribute__((ext_vector_type(4)))  float f32x4;
typedef __attribute__((ext_vector_type(2)))  float f32x2;

union U8 { short8 s; unsigned u[4]; };

__device__ __forceinline__ unsigned short f2bf(float x){
  unsigned u = __float_as_uint(x);
  u += 0x7fffu + ((u >> 16) & 1u);          // RNE
  return (unsigned short)(u >> 16);
}
__device__ __forceinline__ unsigned pk2(float lo, float hi){
  return (unsigned)f2bf(lo) | ((unsigned)f2bf(hi) << 16);
}
__device__ __forceinline__ void swap32(unsigned &a, unsigned &b){
  asm("v_permlane32_swap_b32 %0, %1" : "+v"(a), "+v"(b));
}

#define MFMA32(a,b,c) __builtin_amdgcn_mfma_f32_32x32x16_bf16((a),(b),(c),0,0,0)

// ============================================================================
// Pre-pass: K -> bf16 swizzled tiles; V -> Vt bf16 transposed+swizzled tiles.
// 16 KiB per (batch, 64-kv tile) each. Main kernel stages with global_load_lds
// (linear copy; swizzle pre-baked in ws). (verified round 1-2)
// ============================================================================
__global__ void prep_kv(const float* __restrict__ K, const float* __restrict__ V,
                        const int* __restrict__ VL,
                        char* __restrict__ Kws, char* __restrict__ Vws, int Lk)
{
  const int b = blockIdx.y, t = blockIdx.x, tid = threadIdx.x;
  if (t * 64 >= VL[b]) return;
  const int kv0 = t * 64;
  const size_t tbase = ((size_t)b * (Lk >> 6) + t) << 14;
  const float* Kg = K + ((size_t)b * Lk + kv0) * 128;
  const float* Vg = V + ((size_t)b * Lk + kv0) * 128;
  { // K tile
    const int key = tid >> 2;
    const int c0  = (tid & 3) * 4;
    const float* kp = Kg + key * 128 + c0 * 8;
    f32x4 ka[8];
#pragma unroll
    for (int i = 0; i < 8; ++i) ka[i] = *(const f32x4*)(kp + i * 4);
    char* kb = Kws + tbase + key * 256;
#pragma unroll
    for (int i = 0; i < 4; ++i) {
      U8 u;
      u.u[0] = pk2(ka[2*i].x,   ka[2*i].y);
      u.u[1] = pk2(ka[2*i].z,   ka[2*i].w);
      u.u[2] = pk2(ka[2*i+1].x, ka[2*i+1].y);
      u.u[3] = pk2(ka[2*i+1].z, ka[2*i+1].w);
      *(short8*)(kb + (((c0 + i) ^ (key & 7)) * 16)) = u.s;
    }
  }
  { // V tile (transposed)
    const int kvp = (tid >> 3) * 2;
    const int d0  = (tid & 7) * 16;
    const float* vp = Vg + kvp * 128 + d0;
    f32x4 va[4], vb[4];
#pragma unroll
    for (int i = 0; i < 4; ++i) {
      va[i] = *(const f32x4*)(vp + i * 4);
      vb[i] = *(const f32x4*)(vp + 128 + i * 4);
    }
    char* vbse = Vws + tbase;
#pragma unroll
    for (int j = 0; j < 16; ++j) {
      const int d  = d0 + j;
      const unsigned wv = pk2(va[j >> 2][j & 3], vb[j >> 2][j & 3]);
      const int bp = (kvp >> 3) ^ ((d >> 4) & 7) ^ (d & 7);
      *(unsigned*)(vbse + d * 128 + bp * 16 + (kvp & 7) * 2) = wv;
    }
  }
}

// ============================================================================
// Main kernel: 512 threads, 8 waves, 2 kv-groups. Waves 0-3 (g=0): tiles
// [0,ntA); waves 4-7 (g=1): tiles [ntA,ntall). Round-2-verified primitives
// only (manual pk2, __shfl_xor, linear reductions, no setprio).
// LDS map (132096 B):
//   [0,65536):       K tiles  g*32768 + buf*16384   (epilogue: eb, g=0 only)
//   [65536,131072):  V tiles  65536 + g*32768 + buf*16384
//                    (post-loop: partial O, 16 KiB per wave pair)
//   [131072,132096): partial (m,l), 256 B per wave pair
// ============================================================================
__device__ __forceinline__ void issue_tile2(char* sm, int g, int buf,
                                            const char* Kt, const char* Vt,
                                            int gt, int wl, int lane)
{
  const size_t goff = ((size_t)gt << 14) + (size_t)(wl * 4096 + lane * 16);
  const char* gk = Kt + goff;
  const char* gv = Vt + goff;
  char* lk = sm + (g << 15) + (buf << 14) + wl * 4096;   // +lane*16 implicit
  char* lv = lk + 65536;
#pragma unroll
  for (int i = 0; i < 4; ++i) {
    __builtin_amdgcn_global_load_lds((const __attribute__((address_space(1))) void*)(gk + i * 1024),
                                     (__attribute__((address_space(3))) void*)(lk + i * 1024), 16, 0, 0);
    __builtin_amdgcn_global_load_lds((const __attribute__((address_space(1))) void*)(gv + i * 1024),
                                     (__attribute__((address_space(3))) void*)(lv + i * 1024), 16, 0, 0);
  }
}

__launch_bounds__(512, 1)
__global__ void attn_ws2(const float* __restrict__ Q, const char* __restrict__ Kws,
                         const char* __restrict__ Vws, const int* __restrict__ VL,
                         float* __restrict__ Out, int Lq, int Lk)
{
  __shared__ __align__(16) char sm[132096];
  const int tid  = threadIdx.x;
  const int lane = tid & 63;
  const int w    = tid >> 6;
  const int wl   = w & 3;
  const int g    = w >> 2;
  const int lq   = lane & 31;
  const int hi   = lane >> 5;

  int qt, b;
  if (gridDim.x == 256 && gridDim.y == 1) {
    const int bid = blockIdx.x;
    b  = (bid & 7) | (((bid >> 3) & 1) << 3);
    qt = bid >> 4;
  } else { qt = blockIdx.x; b = blockIdx.y; }

  const int vlb   = VL[b];
  const int ntall = (vlb + 63) >> 6;
  const int ntA   = (ntall + 1) >> 1;
  const int myn   = g ? (ntall - ntA) : ntA;
  const int t0    = g ? ntA : 0;
  const float SCL2 = 0.08838834764831845f * 1.4426950408889634f; // 1/sqrt(128)*log2(e)

  const char* Ktiles = Kws + (((size_t)b * (Lk >> 6)) << 14);
  const char* Vtiles = Vws + (((size_t)b * (Lk >> 6)) << 14);

  if (myn > 0) issue_tile2(sm, g, 0, Ktiles, Vtiles, t0, wl, lane);

  const int qrow  = qt * 128 + wl * 32 + lq;
  const float* Qg = Q + ((size_t)b * Lq + qrow) * 128;

  short8 qf[8];
#pragma unroll
  for (int s8 = 0; s8 < 8; ++s8) {
    f32x4 a = *(const f32x4*)(Qg + s8 * 16 + hi * 8);
    f32x4 c = *(const f32x4*)(Qg + s8 * 16 + hi * 8 + 4);
    U8 u;
    u.u[0] = pk2(a.x, a.y); u.u[1] = pk2(a.z, a.w);
    u.u[2] = pk2(c.x, c.y); u.u[3] = pk2(c.z, c.w);
    qf[s8] = u.s;
  }

  f32x16 accO[4];
#pragma unroll
  for (int i = 0; i < 4; ++i)
#pragma unroll
    for (int r = 0; r < 16; ++r) accO[i][r] = 0.0f;

  float mrun = -1e30f, lsum = 0.0f;

  for (int t = 0; t < ntA; ++t) {
    __syncthreads();   // drains gload_lds for tile t (both groups) + barrier
    if (t + 1 < myn) issue_tile2(sm, g, (t + 1) & 1, Ktiles, Vtiles, t0 + t + 1, wl, lane);

    if (t < myn) {
      const int kbase = (g << 15) + ((t & 1) << 14);
      const int vbase = 65536 + (g << 15) + ((t & 1) << 14);

      // ---- S^T = mfma(K, Q) ----
      f32x16 s0, s1;
#pragma unroll
      for (int r = 0; r < 16; ++r) { s0[r] = 0.0f; s1[r] = 0.0f; }
#pragma unroll
      for (int s8 = 0; s8 < 8; ++s8) {
        const int blk = 2 * s8 + hi;
        short8 k0 = *(const short8*)(sm + kbase + lq * 256        + ((blk ^ (lq & 7)) * 16));
        short8 k1 = *(const short8*)(sm + kbase + (32 + lq) * 256 + ((blk ^ (lq & 7)) * 16));
        s0 = MFMA32(k0, qf[s8], s0);
        s1 = MFMA32(k1, qf[s8], s1);
      }

      // ---- valid_len mask (globally-last, partial tile only) ----
      const int gt = t0 + t;
      if (gt == ntall - 1 && (vlb & 63)) {
        const int kb = gt * 64 + 4 * hi;
#pragma unroll
        for (int r = 0; r < 16; ++r) {
          const int key = kb + (r & 3) + 8 * (r >> 2);
          if (key >= vlb)      s0[r] = -1e30f;
          if (key + 32 >= vlb) s1[r] = -1e30f;
        }
      }

      // ---- online softmax (round-2 style: linear reduce + shfl_xor) ----
      float tmax = -1e30f;
#pragma unroll
      for (int r = 0; r < 16; ++r) { tmax = fmaxf(tmax, s0[r]); tmax = fmaxf(tmax, s1[r]); }
      tmax = fmaxf(tmax, __shfl_xor(tmax, 32, 64));
      const float mnew = fmaxf(mrun, tmax);
      const float mk   = mnew * SCL2;
      float tsum = 0.0f;
#pragma unroll
      for (int r = 0; r < 16; ++r) {
        s0[r] = __builtin_amdgcn_exp2f(s0[r] * SCL2 - mk); tsum += s0[r];
        s1[r] = __builtin_amdgcn_exp2f(s1[r] * SCL2 - mk); tsum += s1[r];
      }
      tsum += __shfl_xor(tsum, 32, 64);
      if (__any(mnew > mrun)) {
        const float corr = __builtin_amdgcn_exp2f((mrun - mnew) * SCL2);
        lsum = lsum * corr + tsum;
#pragma unroll
        for (int i = 0; i < 4; ++i)
#pragma unroll
          for (int r = 0; r < 16; ++r) accO[i][r] *= corr;
      } else {
        lsum += tsum;
      }
      mrun = mnew;

      // ---- P -> bf16 fragments (manual pk2 + swap32; round-2 verified) ----
      U8 pf[4];
      {
        unsigned wt[8]; unsigned a, bx;
#pragma unroll
        for (int j = 0; j < 8; ++j) wt[j] = pk2(s0[2*j], s0[2*j+1]);
        a = wt[0]; bx = wt[2]; swap32(a, bx); pf[0].u[0] = a; pf[0].u[2] = bx;
        a = wt[1]; bx = wt[3]; swap32(a, bx); pf[0].u[1] = a; pf[0].u[3] = bx;
        a = wt[4]; bx = wt[6]; swap32(a, bx); pf[1].u[0] = a; pf[1].u[2] = bx;
        a = wt[5]; bx = wt[7]; swap32(a, bx); pf[1].u[1] = a; pf[1].u[3] = bx;
#pragma unroll
        for (int j = 0; j < 8; ++j) wt[j] = pk2(s1[2*j], s1[2*j+1]);
        a = wt[0]; bx = wt[2]; swap32(a, bx); pf[2].u[0] = a; pf[2].u[2] = bx;
        a = wt[1]; bx = wt[3]; swap32(a, bx); pf[2].u[1] = a; pf[2].u[3] = bx;
        a = wt[4]; bx = wt[6]; swap32(a, bx); pf[3].u[0] = a; pf[3].u[2] = bx;
        a = wt[5]; bx = wt[7]; swap32(a, bx); pf[3].u[1] = a; pf[3].u[3] = bx;
      }

      // ---- O^T += mfma(Vt, P) ----
#pragma unroll
      for (int s = 0; s < 4; ++s) {
#pragma unroll
        for (int dt = 0; dt < 4; ++dt) {
          const int d  = dt * 32 + lq;
          const int bp = (2 * s + hi) ^ ((d >> 4) & 7) ^ (d & 7);
          short8 vf = *(const short8*)(sm + vbase + d * 128 + bp * 16);
          accO[dt] = MFMA32(vf, pf[s].s, accO[dt]);
        }
      }
    }
  }

  // ---- cross-group combine in LDS ----
  __syncthreads();
  if (g) {
    char* pr = sm + 65536 + wl * 16384;
#pragma unroll
    for (int dt = 0; dt < 4; ++dt)
#pragma unroll
      for (int r4 = 0; r4 < 4; ++r4) {
        f32x4 o;
        o.x = accO[dt][r4*4+0]; o.y = accO[dt][r4*4+1];
        o.z = accO[dt][r4*4+2]; o.w = accO[dt][r4*4+3];
        *(f32x4*)(pr + (dt * 4 + r4) * 1024 + lane * 16) = o;
      }
    if (!hi) {
      *(float*)(sm + 131072 + wl * 256 + lq * 8)     = mrun;
      *(float*)(sm + 131072 + wl * 256 + lq * 8 + 4) = lsum;
    }
  }
  __syncthreads();
  if (!g) {
    const float m1 = *(const float*)(sm + 131072 + wl * 256 + lq * 8);
    const float l1 = *(const float*)(sm + 131072 + wl * 256 + lq * 8 + 4);
    const float m  = fmaxf(mrun, m1);
    const float a0 = __builtin_amdgcn_exp2f((mrun - m) * SCL2);
    const float a1 = __builtin_amdgcn_exp2f((m1   - m) * SCL2);
    const float lf = lsum * a0 + l1 * a1;
    const char* pr = sm + 65536 + wl * 16384;
#pragma unroll
    for (int dt = 0; dt < 4; ++dt)
#pragma unroll
      for (int r4 = 0; r4 < 4; ++r4) {
        f32x4 o1 = *(const f32x4*)(pr + (dt * 4 + r4) * 1024 + lane * 16);
        accO[dt][r4*4+0] = accO[dt][r4*4+0] * a0 + o1.x * a1;
        accO[dt][r4*4+1] = accO[dt][r4*4+1] * a0 + o1.y * a1;
        accO[dt][r4*4+2] = accO[dt][r4*4+2] * a0 + o1.z * a1;
        accO[dt][r4*4+3] = accO[dt][r4*4+3] * a0 + o1.w * a1;
      }

    // ---- epilogue: per-wave LDS transpose, coalesced f32 stores ----
    const float inv = 1.0f / lf;
    char* eb = sm + wl * 16384;
#pragma unroll
    for (int dt = 0; dt < 4; ++dt) {
#pragma unroll
      for (int r = 0; r < 16; r += 2) {
        const int d = dt * 32 + (r & 3) + 8 * (r >> 2) + 4 * hi;
        f32x2 o2; o2.x = accO[dt][r] * inv; o2.y = accO[dt][r+1] * inv;
        *(f32x2*)(eb + lq * 512 + (((d >> 2) ^ (lq & 7)) * 16) + (d & 3) * 4) = o2;
      }
    }
    float* Og = Out + ((size_t)b * Lq + qt * 128 + wl * 32) * 128;
#pragma unroll
    for (int pass = 0; pass < 16; ++pass) {
      const int q = pass * 2 + hi;
      f32x4 o4 = *(const f32x4*)(eb + q * 512 + ((lq ^ (q & 7)) * 16));
      *(f32x4*)(Og + q * 128 + lq * 4) = o4;
    }
  }
}

// ============================================================================
// Fallback (round-1 kernel, verified): used only if ws is too small.
// ============================================================================
__device__ __forceinline__ void stage_tile(char* sm, int buf, const float* __restrict__ Kg,
                                           const float* __restrict__ Vg, int kv0, int tid)
{
  {
    const int key = tid >> 2;
    const int c0  = (tid & 3) * 4;
    const float* kp = Kg + (kv0 + key) * 128 + c0 * 8;
    f32x4 ka[8];
#pragma unroll
    for (int i = 0; i < 8; ++i) ka[i] = *(const f32x4*)(kp + i * 4);
    char* kb = sm + buf * 16384 + key * 256;
#pragma unroll
    for (int i = 0; i < 4; ++i) {
      U8 u;
      u.u[0] = pk2(ka[2*i].x,   ka[2*i].y);
      u.u[1] = pk2(ka[2*i].z,   ka[2*i].w);
      u.u[2] = pk2(ka[2*i+1].x, ka[2*i+1].y);
      u.u[3] = pk2(ka[2*i+1].z, ka[2*i+1].w);
      *(short8*)(kb + (((c0 + i) ^ (key & 7)) * 16)) = u.s;
    }
  }
  {
    const int kvp = (tid >> 3) * 2;
    const int d0  = (tid & 7) * 16;
    const float* vp = Vg + (kv0 + kvp) * 128 + d0;
    f32x4 va[4], vb[4];
#pragma unroll
    for (int i = 0; i < 4; ++i) {
      va[i] = *(const f32x4*)(vp + i * 4);
      vb[i] = *(const f32x4*)(vp + 128 + i * 4);
    }
    char* vbse = sm + 32768 + buf * 16384;
#pragma unroll
    for (int j = 0; j < 16; ++j) {
      const int d  = d0 + j;
      const unsigned wv = pk2(va[j >> 2][j & 3], vb[j >> 2][j & 3]);
      const int bp = (kvp >> 3) ^ ((d >> 4) & 7) ^ (d & 7);
      *(unsigned*)(vbse + d * 128 + bp * 16 + (kvp & 7) * 2) = wv;
    }
  }
}

__launch_bounds__(256, 1)
__global__ void attn_fused(const float* __restrict__ Q, const float* __restrict__ K,
                           const float* __restrict__ V, const int* __restrict__ VL,
                           float* __restrict__ Out, int Lq, int Lk)
{
  __shared__ __align__(16) char sm[65536];
  const int tid  = threadIdx.x;
  const int lane = tid & 63;
  const int w    = tid >> 6;
  const int lq   = lane & 31;
  const int hi   = lane >> 5;
  const int b    = blockIdx.y;
  const int vlb  = VL[b];
  const int nt   = (vlb + 63) >> 6;
  const float SCL2 = 0.08838834764831845f * 1.4426950408889634f;

  const float* Kg = K + (size_t)b * Lk * 128;
  const float* Vg = V + (size_t)b * Lk * 128;
  const int qrow  = blockIdx.x * 128 + w * 32 + lq;
  const float* Qg = Q + ((size_t)b * Lq + qrow) * 128;

  short8 qf[8];
#pragma unroll
  for (int s8 = 0; s8 < 8; ++s8) {
    f32x4 a = *(const f32x4*)(Qg + s8 * 16 + hi * 8);
    f32x4 c = *(const f32x4*)(Qg + s8 * 16 + hi * 8 + 4);
    U8 u;
    u.u[0] = pk2(a.x, a.y); u.u[1] = pk2(a.z, a.w);
    u.u[2] = pk2(c.x, c.y); u.u[3] = pk2(c.z, c.w);
    qf[s8] = u.s;
  }

  f32x16 accO[4];
#pragma unroll
  for (int i = 0; i < 4; ++i)
#pragma unroll
    for (int r = 0; r < 16; ++r) accO[i][r] = 0.0f;

  float mrun = -1e30f, lsum = 0.0f;
  stage_tile(sm, 0, Kg, Vg, 0, tid);

  for (int t = 0; t < nt; ++t) {
    __syncthreads();
    const int kbase = (t & 1) * 16384;
    const int vbase = 32768 + (t & 1) * 16384;

    f32x16 s0, s1;
#pragma unroll
    for (int r = 0; r < 16; ++r) { s0[r] = 0.0f; s1[r] = 0.0f; }
#pragma unroll
    for (int s8 = 0; s8 < 8; ++s8) {
      const int blk = 2 * s8 + hi;
      short8 k0 = *(const short8*)(sm + kbase + lq * 256        + ((blk ^ (lq & 7)) * 16));
      short8 k1 = *(const short8*)(sm + kbase + (32 + lq) * 256 + ((blk ^ (lq & 7)) * 16));
      s0 = MFMA32(k0, qf[s8], s0);
      s1 = MFMA32(k1, qf[s8], s1);
    }

    if (t == nt - 1 && (vlb & 63)) {
      const int kb = t * 64 + 4 * hi;
#pragma unroll
      for (int r = 0; r < 16; ++r) {
        const int key = kb + (r & 3) + 8 * (r >> 2);
        if (key >= vlb)      s0[r] = -1e30f;
        if (key + 32 >= vlb) s1[r] = -1e30f;
      }
    }

    float tmax = -1e30f;
#pragma unroll
    for (int r = 0; r < 16; ++r) { tmax = fmaxf(tmax, s0[r]); tmax = fmaxf(tmax, s1[r]); }
    tmax = fmaxf(tmax, __shfl_xor(tmax, 32, 64));
    const float mnew = fmaxf(mrun, tmax);
    const float mk   = mnew * SCL2;
    float tsum = 0.0f;
#pragma unroll
    for (int r = 0; r < 16; ++r) {
      s0[r] = __builtin_amdgcn_exp2f(s0[r] * SCL2 - mk); tsum += s0[r];
      s1[r] = __builtin_amdgcn_exp2f(s1[r] * SCL2 - mk); tsum += s1[r];
    }
    tsum += __shfl_xor(tsum, 32, 64);
    if (__any(mnew > mrun)) {
      const float corr = __builtin_amdgcn_exp2f((mrun - mnew) * SCL2);
      lsum = lsum * corr + tsum;
#pragma unroll
      for (int i = 0; i < 4; ++i)
#pragma unroll
        for (int r = 0; r < 16; ++r) accO[i][r] *= corr;
    } else {
      lsum += tsum;
    }
    mrun = mnew;

    if (t + 1 < nt) stage_tile(sm, (t + 1) & 1, Kg, Vg, (t + 1) * 64, tid);

    U8 pf[4];
    {
      unsigned wt[8]; unsigned a, bx;
#pragma unroll
      for (int j = 0; j < 8; ++j) wt[j] = pk2(s0[2*j], s0[2*j+1]);
      a = wt[0]; bx = wt[2]; swap32(a, bx); pf[0].u[0] = a; pf[0].u[2] = bx;
      a = wt[1]; bx = wt[3]; swap32(a, bx); pf[0].u[1] = a; pf[0].u[3] = bx;
      a = wt[4]; bx = wt[6]; swap32(a, bx); pf[1].u[0] = a; pf[1].u[2] = bx;
      a = wt[5]; bx = wt[7]; swap32(a, bx); pf[1].u[1] = a; pf[1].u[3] = bx;
#pragma unroll
      for (int j = 0; j < 8; ++j) wt[j] = pk2(s1[2*j], s1[2*j+1]);
      a = wt[0]; bx = wt[2]; swap32(a, bx); pf[2].u[0] = a; pf[2].u[2] = bx;
      a = wt[1]; bx = wt[3]; swap32(a, bx); pf[2].u[1] = a; pf[2].u[3] = bx;
      a = wt[4]; bx = wt[6]; swap32(a, bx); pf[3].u[0] = a; pf[3].u[2] = bx;
      a = wt[5]; bx = wt[7]; swap32(a, bx); pf[3].u[1] = a; pf[3].u[3] = bx;
    }

#pragma unroll
    for (int s = 0; s < 4; ++s) {
#pragma unroll
      for (int dt = 0; dt < 4; ++dt) {
        const int d  = dt * 32 + lq;
        const int bp = (2 * s + hi) ^ ((d >> 4) & 7) ^ (d & 7);
        short8 vf = *(const short8*)(sm + vbase + d * 128 + bp * 16);
        accO[dt] = MFMA32(vf, pf[s].s, accO[dt]);
      }
    }
  }

  __syncthreads();
  const float inv = 1.0f / lsum;
  char* eb = sm + w * 16384;
#pragma unroll
  for (int dt = 0; dt < 4; ++dt) {
#pragma unroll
    for (int r = 0; r < 16; r += 2) {
      const int d = dt * 32 + (r & 3) + 8 * (r >> 2) + 4 * hi;
      f32x2 o2; o2.x = accO[dt][r] * inv; o2.y = accO[dt][r+1] * inv;
      *(f32x2*)(eb + lq * 512 + (((d >> 2) ^ (lq & 7)) * 16) + (d & 3) * 4) = o2;
    }
  }
  float* Og = Out + ((size_t)b * Lq + blockIdx.x * 128 + w * 32) * 128;
#pragma unroll
  for (int pass = 0; pass < 16; ++pass) {
    const int q = pass * 2 + hi;
    f32x4 o4 = *(const f32x4*)(eb + q * 512 + ((lq ^ (q & 7)) * 16));
    *(f32x4*)(Og + q * 128 + lq * 4) = o4;
  }
}

extern "C" void kernel_launch(void* const* d_in, const int* in_sizes, int n_in,
                              void* d_out, int out_size, void* d_ws, size_t ws_size,
                              hipStream_t stream)
{
  (void)n_in; (void)out_size;
  const float* Q  = (const float*)d_in[0];
  const float* K  = (const float*)d_in[1];
  const float* V  = (const float*)d_in[2];
  const int*   VL = (const int*)d_in[3];
  float* Out = (float*)d_out;
  const int B  = in_sizes[3];
  const int Lq = in_sizes[0] / (B * 128);
  const int Lk = in_sizes[1] / (B * 128);

  const size_t kbytes = (size_t)B * Lk * 256;   // bf16 swizzled K tiles
  const size_t need   = kbytes * 2;             // + Vt tiles
  if (ws_size >= need && (Lk & 63) == 0 && (Lq & 127) == 0) {
    char* Kws = (char*)d_ws;
    char* Vws = Kws + kbytes;
    dim3 pg(Lk / 64, B);
    prep_kv<<<pg, 256, 0, stream>>>(K, V, VL, Kws, Vws, Lk);
    if (Lq == 2048 && B == 16) {
      attn_ws2<<<256, 512, 0, stream>>>(Q, Kws, Vws, VL, Out, Lq, Lk);
    } else {
      dim3 g(Lq / 128, B);
      attn_ws2<<<g, 512, 0, stream>>>(Q, Kws, Vws, VL, Out, Lq, Lk);
    }
  } else {
    dim3 g(Lq / 128, B);
    attn_fused<<<g, 256, 0, stream>>>(Q, K, V, VL, Out, Lq, Lk);
  }
}